// Round 1
// 1629.645 us; speedup vs baseline: 1.0789x; 1.0789x over previous
//
#include <hip/hip_runtime.h>

namespace {

constexpr int B = 64;
constexpr int L = 2048;
constexpr int Q = 256;
constexpr int S = 26;
constexpr float EPS = 1e-16f;
constexpr size_t POST = (size_t)B * L * Q;  // loglik offset in d_out

typedef _Float16 h2 __attribute__((ext_vector_type(2)));
typedef _Float16 f16x8 __attribute__((ext_vector_type(8)));
typedef float f32x4 __attribute__((ext_vector_type(4)));

#define MFMA16(a, b, c) __builtin_amdgcn_mfma_f32_16x16x32_f16((a), (b), (c), 0, 0, 0)

struct Smem {
  alignas(16) _Float16 vb[2][Q];     // scaled linear recursion vector (f16), dbuf
  alignas(16) _Float16 rowh[2][32];  // staged input row, f16 hi part (padded 26->32)
  alignas(16) _Float16 rowl[2][32];  // f16 lo residual part
  float sh[2];                       // state-0 anchor broadcast, dbuf
  alignas(16) float afin[Q];         // final alpha for exact loglik
};

__device__ __forceinline__ float wave_max64(float x) {
#pragma unroll
  for (int off = 32; off > 0; off >>= 1) x = fmaxf(x, __shfl_xor(x, off, 64));
  return x;
}
__device__ __forceinline__ float wave_sum64(float x) {
#pragma unroll
  for (int off = 32; off > 0; off >>= 1) x += __shfl_xor(x, off, 64);
  return x;
}

// Emission B-operand frags: expB^T[s][state], hi/lo split for ~f32 accuracy.
// B-frag layout (16x16x32): lane l holds B[(l>>4)*8 + j][l&15], j=0..7.
__device__ __forceinline__ void load_emit_frags(const float* __restrict__ log_B,
                                                int c0, int c1, int g, int q,
                                                f16x8& Bh0, f16x8& Bl0,
                                                f16x8& Bh1, f16x8& Bl1) {
#pragma unroll
  for (int j = 0; j < 8; ++j) {
    const int s = g * 8 + j;
    const float v0 = (s < S) ? __expf(log_B[(size_t)(c0 + q) * S + s]) : 0.f;
    const float v1 = (s < S) ? __expf(log_B[(size_t)(c1 + q) * S + s]) : 0.f;
    const _Float16 h0 = (_Float16)v0, h1 = (_Float16)v1;
    Bh0[j] = h0; Bl0[j] = (_Float16)(v0 - (float)h0);
    Bh1[j] = h1; Bl1[j] = (_Float16)(v1 - (float)h1);
  }
}

// Stage one input row (26 f32) into LDS as f16 hi + f16 residual, padded to 32.
// Called by wave 0, lanes 0..15 (lanes 13..15 write zero pad).
__device__ __forceinline__ void stage_row(Smem& sm, int buf, int lane, float2 gg) {
  _Float16 ah = (_Float16)0.f, bh = (_Float16)0.f;
  _Float16 al = (_Float16)0.f, bl = (_Float16)0.f;
  if (lane < 13) {
    ah = (_Float16)gg.x; bh = (_Float16)gg.y;
    al = (_Float16)(gg.x - (float)ah);
    bl = (_Float16)(gg.y - (float)bh);
  }
  ((h2*)sm.rowh[buf])[lane] = h2{ah, bh};
  ((h2*)sm.rowl[buf])[lane] = h2{al, bl};
}

// emit = (xh+xl) . (Bh+Bl) ~= xh*Bl + xl*Bh + xh*Bh  (3-term, ~f32 accurate)
__device__ __forceinline__ void emit_mfma(const f16x8& xh, const f16x8& xl,
                                          const f16x8& Bh0, const f16x8& Bl0,
                                          const f16x8& Bh1, const f16x8& Bl1,
                                          f32x4& E0, f32x4& E1) {
  const f32x4 Z = {0.f, 0.f, 0.f, 0.f};
  E0 = MFMA16(xh, Bl0, Z);
  E0 = MFMA16(xl, Bh0, E0);
  E0 = MFMA16(xh, Bh0, E0);
  E1 = MFMA16(xh, Bl1, Z);
  E1 = MFMA16(xl, Bh1, E1);
  E1 = MFMA16(xh, Bh1, E1);
}

// x = v^T * T for this wave's two 16-state column tiles; K=256 as 8 frags,
// split into two 4-deep chains per tile for ILP. Only D row 0 (reg 0,
// lanes 0..15) is meaningful; garbage in A rows 1..15 cannot reach row 0.
__device__ __forceinline__ void matvec_mfma(const f16x8* va, const f16x8* T0,
                                            const f16x8* T1, float& x0, float& x1) {
  const f32x4 Z = {0.f, 0.f, 0.f, 0.f};
  f32x4 X0a = MFMA16(va[0], T0[0], Z);
  f32x4 X1a = MFMA16(va[0], T1[0], Z);
  f32x4 X0b = MFMA16(va[4], T0[4], Z);
  f32x4 X1b = MFMA16(va[4], T1[4], Z);
#pragma unroll
  for (int f = 1; f < 4; ++f) {
    X0a = MFMA16(va[f], T0[f], X0a);
    X1a = MFMA16(va[f], T1[f], X1a);
    X0b = MFMA16(va[f + 4], T0[f + 4], X0b);
    X1b = MFMA16(va[f + 4], T1[f + 4], X1b);
  }
  x0 = X0a[0] + X0b[0];
  x1 = X1a[0] + X1b[0];
}

// Sparse frag reads: only lanes with (lane&15)==0 carry A-operand data
// (row 0 of the 16x32 A frag). Exec-masked -> 4 active lanes per ds_read.
__device__ __forceinline__ void read_frags(Smem& sm, int p, int g,
                                           f16x8& xh, f16x8& xl, f16x8* va) {
  xh = *(const f16x8*)(sm.rowh[p] + g * 8);
  xl = *(const f16x8*)(sm.rowl[p] + g * 8);
  const _Float16* vbp = sm.vb[p];
#pragma unroll
  for (int f = 0; f < 8; ++f) va[f] = *(const f16x8*)(vbp + f * 32 + g * 8);
}

// ---------------- forward ----------------
// Linear-space recursion with one-step-stale state-0 anchor (identical math
// to the verified baseline); matvec+emission moved onto the matrix pipe.
__device__ __forceinline__ void fwd_impl(int b, const float* __restrict__ inputs,
                                         const float* __restrict__ log_A,
                                         const float* __restrict__ log_pi,
                                         const float* __restrict__ log_B,
                                         float* __restrict__ out, Smem& sm) {
  const int tid = threadIdx.x, w = tid >> 6, lane = tid & 63;
  const int g = lane >> 4, q = lane & 15;
  const int c0 = w * 32, c1 = c0 + 16;
  const bool rdl = (q == 0);
  const bool epi = (lane < 16);
  const bool stg = (w == 0) && (lane < 16);

  // Static B-operand frags (persistent in VGPRs): T[k][c] = exp(log_A[k*Q+c]).
  f16x8 T0[8], T1[8];
#pragma unroll
  for (int f = 0; f < 8; ++f) {
#pragma unroll
    for (int j = 0; j < 8; ++j) {
      const int k = f * 32 + g * 8 + j;
      T0[f][j] = (_Float16)__expf(log_A[(size_t)k * Q + c0 + q]);
      T1[f][j] = (_Float16)__expf(log_A[(size_t)k * Q + c1 + q]);
    }
  }
  f16x8 Bh0, Bl0, Bh1, Bl1;
  load_emit_frags(log_B, c0, c1, g, q, Bh0, Bl0, Bh1, Bl1);

  const float2* __restrict__ inp2 = (const float2*)(inputs + (size_t)b * L * S);
  float* __restrict__ post_b = out + (size_t)b * L * Q;

  // init: stage rows 0 (buf1) and 1 (buf0)
  if (stg) {
    float2 g0, g1;
    if (lane < 13) { g0 = inp2[lane]; g1 = inp2[13 + lane]; }
    stage_row(sm, 1, lane, g0);
    stage_row(sm, 0, lane, g1);
  }
  __syncthreads();

  f16x8 xh = {}, xl = {};
  f16x8 va[8];
#pragma unroll
  for (int f = 0; f < 8; ++f) va[f] = f16x8{};

  // t = 0
  if (rdl) {
    xh = *(const f16x8*)(sm.rowh[1] + g * 8);
    xl = *(const f16x8*)(sm.rowl[1] + g * 8);
  }
  f32x4 E0, E1;
  emit_mfma(xh, xl, Bh0, Bl0, Bh1, Bl1, E0, E1);
  float zh0 = 1.f, zh1 = 1.f, rdp_h = 0.f;  // alpha_t = log(zh) + rdp_h (deferred)
  if (epi) {
    zh0 = (E0[0] + EPS) * __expf(log_pi[c0 + lane]);
    zh1 = (E1[0] + EPS) * __expf(log_pi[c1 + lane]);
  }
  if (tid == 0) sm.sh[0] = __logf(zh0);  // alpha_0(0)
  __syncthreads();
  float rd_prev = sm.sh[0];
  if (epi) {
    const float sc = __expf(-rd_prev);
    sm.vb[0][c0 + lane] = (_Float16)(zh0 * sc);
    sm.vb[0][c1 + lane] = (_Float16)(zh1 * sc);
  }
  __syncthreads();

  int p = 0;
  for (int t = 1; t < L; ++t) {
    const float rd = sm.sh[p];  // alpha_{t-1}(0)
    float2 gg;
    const int tt = (t + 1 < L) ? t + 1 : L - 1;
    if (w == 0 && lane < 13) gg = inp2[(size_t)tt * 13 + lane];
    if (epi) {  // delayed store of alpha_{t-1} (log off the critical path)
      const float a0 = __logf(zh0) + rdp_h;
      const float a1 = __logf(zh1) + rdp_h;
      post_b[(size_t)(t - 1) * Q + c0 + lane] = a0;
      post_b[(size_t)(t - 1) * Q + c1 + lane] = a1;
    }
    if (rdl) read_frags(sm, p, g, xh, xl, va);
    f32x4 E0_, E1_;
    emit_mfma(xh, xl, Bh0, Bl0, Bh1, Bl1, E0_, E1_);
    float x0, x1;
    matvec_mfma(va, T0, T1, x0, x1);
    const float gam = __expf(rd_prev - rd);
    if (epi) {
      const float e0 = E0_[0] + EPS, e1 = E1_[0] + EPS;
      const float z0 = x0 * e0, z1 = x1 * e1;
      sm.vb[p ^ 1][c0 + lane] = (_Float16)(z0 * gam);
      sm.vb[p ^ 1][c1 + lane] = (_Float16)(z1 * gam);
      if (tid == 0) sm.sh[p ^ 1] = __logf(z0) + rd_prev;  // alpha_t(0)
      zh0 = z0; zh1 = z1;
    }
    rdp_h = rd_prev;
    rd_prev = rd;
    if (stg) stage_row(sm, p ^ 1, lane, gg);
    __syncthreads();
    p ^= 1;
  }

  // epilogue: final alpha store + exact loglik
  if (epi) {
    const float a0 = __logf(zh0) + rdp_h;
    const float a1 = __logf(zh1) + rdp_h;
    post_b[(size_t)(L - 1) * Q + c0 + lane] = a0;
    post_b[(size_t)(L - 1) * Q + c1 + lane] = a1;
    sm.afin[c0 + lane] = a0;
    sm.afin[c1 + lane] = a1;
  }
  __syncthreads();
  if (w == 0) {
    float4 fa = ((const float4*)sm.afin)[lane];
    float m = fmaxf(fmaxf(fa.x, fa.y), fmaxf(fa.z, fa.w));
    m = wave_max64(m);
    float ss = __expf(fa.x - m) + __expf(fa.y - m) + __expf(fa.z - m) + __expf(fa.w - m);
    ss = wave_sum64(ss);
    if (lane == 0) out[POST + b] = __logf(ss) + m;
  }
}

// ---------------- backward ----------------
// MODE 0: beta -> ws (concurrent with fwd). MODE 1: fused RMW post += beta - ll.
template <int MODE>
__device__ __forceinline__ void bwd_impl(int b, const float* __restrict__ inputs,
                                         const float* __restrict__ log_A,
                                         const float* __restrict__ log_B,
                                         float* __restrict__ out,
                                         float* __restrict__ ws, Smem& sm) {
  const int tid = threadIdx.x, w = tid >> 6, lane = tid & 63;
  const int g = lane >> 4, q = lane & 15;
  const int c0 = w * 32, c1 = c0 + 16;
  const bool rdl = (q == 0);
  const bool epi = (lane < 16);
  const bool stg = (w == 0) && (lane < 16);

  // bwd matvec is with A (not A^T): T[k][c] = exp(log_A[c*Q + k]).
  f16x8 T0[8], T1[8];
#pragma unroll
  for (int f = 0; f < 8; ++f) {
#pragma unroll
    for (int j = 0; j < 8; ++j) {
      const int k = f * 32 + g * 8 + j;
      T0[f][j] = (_Float16)__expf(log_A[(size_t)(c0 + q) * Q + k]);
      T1[f][j] = (_Float16)__expf(log_A[(size_t)(c1 + q) * Q + k]);
    }
  }
  f16x8 Bh0, Bl0, Bh1, Bl1;
  load_emit_frags(log_B, c0, c1, g, q, Bh0, Bl0, Bh1, Bl1);

  const float2* __restrict__ inp2 = (const float2*)(inputs + (size_t)b * L * S);
  float* __restrict__ post_b = out + (size_t)b * L * Q;
  float* __restrict__ ws_b = ws + (size_t)b * L * Q;

  float ll = 0.f, a_h0 = 0.f, a_h1 = 0.f;
  if (MODE == 1) {
    ll = out[POST + b];
    if (epi) {
      a_h0 = post_b[(size_t)(L - 1) * Q + c0 + lane];
      a_h1 = post_b[(size_t)(L - 1) * Q + c1 + lane];
    }
  }

  // init: stage rows L-1 (buf1) and L-2 (buf0)
  if (stg) {
    float2 g0, g1;
    if (lane < 13) {
      g0 = inp2[(size_t)(L - 1) * 13 + lane];
      g1 = inp2[(size_t)(L - 2) * 13 + lane];
    }
    stage_row(sm, 1, lane, g0);
    stage_row(sm, 0, lane, g1);
  }
  __syncthreads();

  f16x8 xh = {}, xl = {};
  f16x8 va[8];
#pragma unroll
  for (int f = 0; f < 8; ++f) va[f] = f16x8{};

  if (rdl) {
    xh = *(const f16x8*)(sm.rowh[1] + g * 8);
    xl = *(const f16x8*)(sm.rowl[1] + g * 8);
  }
  f32x4 E0, E1;
  emit_mfma(xh, xl, Bh0, Bl0, Bh1, Bl1, E0, E1);
  float e0i = 1.f, e1i = 1.f;
  if (epi) { e0i = E0[0] + EPS; e1i = E1[0] + EPS; }
  if (tid == 0) sm.sh[0] = __logf(e0i);  // u_{L-1}(0)
  __syncthreads();
  float rd_prev = sm.sh[0];
  if (epi) {
    const float sc = __expf(-rd_prev);
    sm.vb[0][c0 + lane] = (_Float16)(e0i * sc);
    sm.vb[0][c1 + lane] = (_Float16)(e1i * sc);
  }
  float rh0 = 1.f, rh1 = 1.f, rdp_h = 0.f;  // beta_{L-1} = log(1)+0 = 0
  __syncthreads();

  int p = 0;
  for (int t = L - 2; t >= 0; --t) {
    const float rd = sm.sh[p];
    float2 gg;
    const int tt = (t > 0) ? t - 1 : 0;
    if (w == 0 && lane < 13) gg = inp2[(size_t)tt * 13 + lane];
    if (epi) {  // delayed output for row t+1: beta = log(raw) + anchor
      const float b0 = __logf(rh0) + rdp_h;
      const float b1 = __logf(rh1) + rdp_h;
      if (MODE == 0) {
        ws_b[(size_t)(t + 1) * Q + c0 + lane] = b0;
        ws_b[(size_t)(t + 1) * Q + c1 + lane] = b1;
      } else {
        post_b[(size_t)(t + 1) * Q + c0 + lane] = a_h0 + b0 - ll;
        post_b[(size_t)(t + 1) * Q + c1 + lane] = a_h1 + b1 - ll;
        a_h0 = post_b[(size_t)t * Q + c0 + lane];  // prefetch alpha_t
        a_h1 = post_b[(size_t)t * Q + c1 + lane];
      }
    }
    if (rdl) read_frags(sm, p, g, xh, xl, va);
    f32x4 E0_, E1_;
    emit_mfma(xh, xl, Bh0, Bl0, Bh1, Bl1, E0_, E1_);
    float r0, r1;
    matvec_mfma(va, T0, T1, r0, r1);
    const float gam = __expf(rd_prev - rd);
    if (epi) {
      const float e0 = E0_[0] + EPS, e1 = E1_[0] + EPS;
      const float z0 = r0 * e0, z1 = r1 * e1;
      sm.vb[p ^ 1][c0 + lane] = (_Float16)(z0 * gam);
      sm.vb[p ^ 1][c1 + lane] = (_Float16)(z1 * gam);
      if (tid == 0) sm.sh[p ^ 1] = __logf(z0) + rd_prev;  // u_t(0)=beta+log(e)
      rh0 = r0; rh1 = r1;
    }
    rdp_h = rd_prev;
    rd_prev = rd;
    if (stg) stage_row(sm, p ^ 1, lane, gg);
    __syncthreads();
    p ^= 1;
  }

  // epilogue: row 0
  if (epi) {
    const float b0 = __logf(rh0) + rdp_h;
    const float b1 = __logf(rh1) + rdp_h;
    if (MODE == 0) {
      ws_b[c0 + lane] = b0;
      ws_b[c1 + lane] = b1;
    } else {
      post_b[c0 + lane] = a_h0 + b0 - ll;
      post_b[c1 + lane] = a_h1 + b1 - ll;
    }
  }
}

// ---------------- kernels ----------------
__global__ __launch_bounds__(512, 2)
void hmm_fwdbwd(const float* __restrict__ inputs, const float* __restrict__ log_A,
                const float* __restrict__ log_pi, const float* __restrict__ log_B,
                float* __restrict__ out, float* __restrict__ ws) {
  __shared__ Smem sm;
  if (blockIdx.x < B) fwd_impl(blockIdx.x, inputs, log_A, log_pi, log_B, out, sm);
  else                bwd_impl<0>(blockIdx.x - B, inputs, log_A, log_B, out, ws, sm);
}

__global__ __launch_bounds__(256)
void hmm_combine(const float* __restrict__ ws, float* __restrict__ out) {
  const size_t idx = (size_t)blockIdx.x * 256 + threadIdx.x;  // float4 index
  const int b = (int)(idx >> 17);  // L*Q/4 = 131072 float4 per batch
  const float ll = out[POST + b];
  float4 a = ((const float4*)out)[idx];
  const float4 be = ((const float4*)ws)[idx];
  a.x += be.x - ll;
  a.y += be.y - ll;
  a.z += be.z - ll;
  a.w += be.w - ll;
  ((float4*)out)[idx] = a;
}

__global__ __launch_bounds__(512, 2)
void hmm_fwd_only(const float* __restrict__ inputs, const float* __restrict__ log_A,
                  const float* __restrict__ log_pi, const float* __restrict__ log_B,
                  float* __restrict__ out) {
  __shared__ Smem sm;
  fwd_impl(blockIdx.x, inputs, log_A, log_pi, log_B, out, sm);
}

__global__ __launch_bounds__(512, 2)
void hmm_bwd_fused(const float* __restrict__ inputs, const float* __restrict__ log_A,
                   const float* __restrict__ log_B, float* __restrict__ out) {
  __shared__ Smem sm;
  bwd_impl<1>(blockIdx.x, inputs, log_A, log_B, out, nullptr, sm);
}

}  // namespace

extern "C" void kernel_launch(void* const* d_in, const int* in_sizes, int n_in,
                              void* d_out, int out_size, void* d_ws, size_t ws_size,
                              hipStream_t stream) {
  const float* inputs = (const float*)d_in[0];
  const float* log_A  = (const float*)d_in[1];
  const float* log_pi = (const float*)d_in[2];
  const float* log_B  = (const float*)d_in[3];
  float* out = (float*)d_out;
  float* ws  = (float*)d_ws;

  if (ws_size >= POST * sizeof(float)) {
    hipLaunchKernelGGL(hmm_fwdbwd, dim3(2 * B), dim3(512), 0, stream,
                       inputs, log_A, log_pi, log_B, out, ws);
    hipLaunchKernelGGL(hmm_combine, dim3((unsigned)(POST / 4 / 256)), dim3(256), 0, stream,
                       ws, out);
  } else {
    hipLaunchKernelGGL(hmm_fwd_only, dim3(B), dim3(512), 0, stream,
                       inputs, log_A, log_pi, log_B, out);
    hipLaunchKernelGGL(hmm_bwd_fused, dim3(B), dim3(512), 0, stream,
                       inputs, log_A, log_B, out);
  }
}